// Round 5
// baseline (299.108 us; speedup 1.0000x reference)
//
#include <hip/hip_runtime.h>
#include <stdint.h>

// CIN forward, MI355X. R5 = R4 with the cvt_pkrtz type fix.
// 32x32x16 fp16 MFMA, 512-thr blocks, 2 batches/block, grid 512
// (2 blocks/CU = 4 waves/SIMD). 8 waves = batch(2) x ntile(2) x ohalf(2):
// every W frag consumed by 4 waves -> W L2 traffic 1.15 GB. 2-channel
// double-buffered W prefetch: issue-to-use = 8 MFMAs > L2 latency.

typedef __attribute__((ext_vector_type(8))) _Float16 f16x8;
typedef __attribute__((ext_vector_type(2))) _Float16 f16x2;
typedef __attribute__((ext_vector_type(16))) float f32x16;
typedef __attribute__((ext_vector_type(4))) float f32x4;
typedef __attribute__((ext_vector_type(4))) int i32x4;

union AB {
  i32x4 i;
  f16x8 h;
  uint32_t u[4];
};

static __device__ __forceinline__ uint32_t pkmul(uint32_t a, uint32_t b) {
  f16x2 r = __builtin_bit_cast(f16x2, a) * __builtin_bit_cast(f16x2, b);
  return __builtin_bit_cast(uint32_t, r);  // one v_pk_mul_f16
}
static __device__ __forceinline__ uint32_t pkcvt(float a, float b) {
  return __builtin_bit_cast(uint32_t, __builtin_amdgcn_cvt_pkrtz(a, b));
}

#define HP 136  // hT row pad: 272B stride (16B-aligned rows for ds_read_b128)

__global__ __launch_bounds__(512, 4) void cin_main(
    const float* __restrict__ x, const uint16_t* __restrict__ wp,
    const float* __restrict__ bias0, const float* __restrict__ bias1,
    const float* __restrict__ bias2, float* __restrict__ out) {
  __shared__ __align__(16) uint16_t hT[2][64][HP];  // [batch][d][chan] fp16
  __shared__ float sOut[2][2][128];                 // [batch][ntile][o] partials

  const int tid = threadIdx.x;
  const int w = tid >> 6, lane = tid & 63;
  const int p = w >> 2;          // batch
  const int nt = (w >> 1) & 1;   // d-tile (32-wide)
  const int og = w & 1;          // o-half: o-tiles {2og, 2og+1} (32-wide each)
  const int l5 = lane >> 5, l31 = lane & 31;
  const int dd = nt * 32 + l31;  // this lane's d (B/C col)
  const int bb = blockIdx.x * 2;

  // ---- stage x -> hT[p][d][m] fp16 (layer-0 h == x; 32 channels)
  for (int e = tid; e < 4096; e += 512) {
    int p2 = e >> 11, m = (e >> 6) & 31, d = e & 63;
    hT[p2][d][m] =
        __builtin_bit_cast(uint16_t, (_Float16)x[(size_t)(bb + p2) * 2048 + m * 64 + d]);
  }
  __syncthreads();

  // ---- x B-frags (loop-invariant): xf[kh].j = x[m=kh*16+l5*8+j][dd]
  AB xf[2];
#pragma unroll
  for (int kh = 0; kh < 2; ++kh)
    xf[kh].i = *(const i32x4*)&hT[p][dd][kh * 16 + l5 * 8];  // ds_read_b128

  f32x16 acc[2];

#pragma unroll
  for (int L = 0; L < 3; ++L) {
    const int Kch = (L == 0) ? 32 : 128;
    const uint16_t* wl = (L == 0) ? wp : (L == 1) ? wp + 131072 : wp + 655360;
    const float* bias = (L == 0) ? bias0 : (L == 1) ? bias1 : bias2;

    // packed W frag elems: ((ot*Kch + c)*2 + kh)*512 + lane*8
    const uint16_t* wptr[2];
    wptr[0] = wl + (size_t)(og * 2 + 0) * Kch * 1024 + lane * 8;
    wptr[1] = wl + (size_t)(og * 2 + 1) * Kch * 1024 + lane * 8;

#pragma unroll
    for (int g = 0; g < 2; ++g)
#pragma unroll
      for (int r = 0; r < 16; ++r) acc[g][r] = 0.f;

    AB bufA[2][2][2], bufB[2][2][2];  // [cc][g][kh]

    auto loadW = [&](AB (&buf)[2][2][2], int c) {
#pragma unroll
      for (int cc = 0; cc < 2; ++cc)
#pragma unroll
        for (int g = 0; g < 2; ++g)
#pragma unroll
          for (int kh = 0; kh < 2; ++kh)
            buf[cc][g][kh].i =
                *(const i32x4*)(wptr[g] + (size_t)(c + cc) * 1024 + kh * 512);
    };
    auto compute2 = [&](int c0, AB (&buf)[2][2][2]) {
      uint32_t hv = *(const uint32_t*)&hT[p][dd][c0];  // (h_c0, h_c0+1) fp16
#pragma unroll
      for (int cc = 0; cc < 2; ++cc) {
        uint32_t hd = __builtin_amdgcn_perm(hv, hv, cc ? 0x03020302u : 0x01000100u);
        AB bf0, bf1;  // P[c*32 + kh*16 + k][dd] = h[c,dd] * x[kh*16+k][dd]
#pragma unroll
        for (int k = 0; k < 4; ++k) {
          bf0.u[k] = pkmul(hd, xf[0].u[k]);
          bf1.u[k] = pkmul(hd, xf[1].u[k]);
        }
#pragma unroll
        for (int g = 0; g < 2; ++g) {
          acc[g] = __builtin_amdgcn_mfma_f32_32x32x16_f16(buf[cc][g][0].h, bf0.h, acc[g], 0, 0, 0);
          acc[g] = __builtin_amdgcn_mfma_f32_32x32x16_f16(buf[cc][g][1].h, bf1.h, acc[g], 0, 0, 0);
        }
      }
    };

    loadW(bufA, 0);
#pragma unroll 1
    for (int c0 = 0; c0 < Kch; c0 += 4) {
      loadW(bufB, c0 + 2);
      compute2(c0, bufA);
      loadW(bufA, (c0 + 4 < Kch) ? c0 + 4 : 0);  // wrap: harmless re-load
      compute2(c0 + 2, bufB);
    }

    // ---- bias + ReLU. C layout: col(d)=l31, row = (r&3) + 8*(r>>2) + 4*l5
#pragma unroll
    for (int g = 0; g < 2; ++g)
#pragma unroll
      for (int q4 = 0; q4 < 4; ++q4) {
        f32x4 bv = *(const f32x4*)(bias + (og * 2 + g) * 32 + 8 * q4 + 4 * l5);
#pragma unroll
        for (int r = 0; r < 4; ++r)
          acc[g][q4 * 4 + r] = fmaxf(acc[g][q4 * 4 + r] + bv[r], 0.f);
      }

    // ---- d-partials: butterfly over the 32 d-lanes, write sOut
#pragma unroll
    for (int g = 0; g < 2; ++g)
#pragma unroll
      for (int r = 0; r < 16; ++r) {
        float s = acc[g][r];
        s += __shfl_xor(s, 1);
        s += __shfl_xor(s, 2);
        s += __shfl_xor(s, 4);
        s += __shfl_xor(s, 8);
        s += __shfl_xor(s, 16);
        if (l31 == 0)
          sOut[p][nt][(og * 2 + g) * 32 + (r & 3) + 8 * (r >> 2) + 4 * l5] = s;
      }

    __syncthreads();  // hT reads done; sOut partials complete

    if (L < 2) {  // next-layer h -> hT (disjoint [p][dd] rows per wave)
#pragma unroll
      for (int g = 0; g < 2; ++g)
#pragma unroll
        for (int q4 = 0; q4 < 4; ++q4) {
          uint2 pk;
          pk.x = pkcvt(acc[g][q4 * 4 + 0], acc[g][q4 * 4 + 1]);
          pk.y = pkcvt(acc[g][q4 * 4 + 2], acc[g][q4 * 4 + 3]);
          *(uint2*)&hT[p][dd][(og * 2 + g) * 32 + 8 * q4 + 4 * l5] = pk;
        }
    }

    // combine d-halves -> out (coalesced; 256 lanes = 2 batches x 128 o)
    if (tid < 256) {
      int b2 = tid >> 7, o = tid & 127;
      out[(size_t)(bb + b2) * 384 + L * 128 + o] = sOut[b2][0][o] + sOut[b2][1][o];
    }

    if (L < 2) __syncthreads();  // hT writes visible before next K-loop
  }
}

// Pre-pass: W fp32 -> fp16, 32x32x16 A-frag-major:
// flat idx = ((ot*Kch + c)*2 + kh)*64 + lane, 8 elems/thread.
// A[m = lane&31][k = (lane>>5)*8 + j], k_in = c*32 + kh*16 + k.
__global__ void pack_w(const float* __restrict__ W, uint16_t* __restrict__ Wp,
                       int kshift) {
  const int Kch = 1 << kshift;
  int idx = blockIdx.x * 256 + threadIdx.x;
  int lane = idx & 63;
  int kh = (idx >> 6) & 1;
  int c = (idx >> 7) & (Kch - 1);
  int ot = idx >> (7 + kshift);
  const float* src = W + (size_t)(ot * 32 + (lane & 31)) * (Kch * 32) +
                     c * 32 + kh * 16 + (lane >> 5) * 8;
  uint4 val;
  val.x = pkcvt(src[0], src[1]);
  val.y = pkcvt(src[2], src[3]);
  val.z = pkcvt(src[4], src[5]);
  val.w = pkcvt(src[6], src[7]);
  *(uint4*)(Wp + (size_t)idx * 8) = val;
}

extern "C" void kernel_launch(void* const* d_in, const int* in_sizes, int n_in,
                              void* d_out, int out_size, void* d_ws, size_t ws_size,
                              hipStream_t stream) {
  (void)in_sizes; (void)n_in; (void)out_size; (void)ws_size;
  const float* x  = (const float*)d_in[0];
  const float* W0 = (const float*)d_in[1];
  const float* b0 = (const float*)d_in[2];
  const float* W1 = (const float*)d_in[3];
  const float* b1 = (const float*)d_in[4];
  const float* W2 = (const float*)d_in[5];
  const float* b2 = (const float*)d_in[6];
  uint16_t* wpacked = (uint16_t*)d_ws;  // 2.25 MB of ws

  hipLaunchKernelGGL(pack_w, dim3(64),  dim3(256), 0, stream, W0, wpacked, 5);
  hipLaunchKernelGGL(pack_w, dim3(256), dim3(256), 0, stream, W1, wpacked + 131072, 7);
  hipLaunchKernelGGL(pack_w, dim3(256), dim3(256), 0, stream, W2, wpacked + 655360, 7);
  hipLaunchKernelGGL(cin_main, dim3(512), dim3(512), 0, stream,
                     x, wpacked, b0, b1, b2, (float*)d_out);
}

// Round 7
// 201.123 us; speedup vs baseline: 1.4872x; 1.4872x over previous
//
#include <hip/hip_runtime.h>
#include <stdint.h>

// CIN forward, MI355X. R7 = R6 with the pipeline hazard fixed:
// consume-then-reload slot rotation (R6 overwrote slot 0 BEFORE computing
// with it -> wrong W, absmax 33.5). Depth-2 rotation (step 4), wbuf 32 VGPRs
// -> est ~103 total, fits 4 waves/SIMD at launch_bounds(512,4).
// 16x16x32 f16 MFMA, 8 acc chains/wave; perm-based h splat; hv double-buffer.
// 512-thr blocks, 2 batches/block, grid 512; single coalesced pack kernel.

typedef __attribute__((ext_vector_type(8))) _Float16 f16x8;
typedef __attribute__((ext_vector_type(2))) _Float16 f16x2;
typedef __attribute__((ext_vector_type(4))) float f32x4;
typedef __attribute__((ext_vector_type(4))) int i32x4;

union AB {
  i32x4 i;
  f16x8 h;
  uint32_t u[4];
};

static __device__ __forceinline__ uint32_t pkmul(uint32_t a, uint32_t b) {
  f16x2 r = __builtin_bit_cast(f16x2, a) * __builtin_bit_cast(f16x2, b);
  return __builtin_bit_cast(uint32_t, r);  // one v_pk_mul_f16
}
static __device__ __forceinline__ uint32_t pkcvt(float a, float b) {
  return __builtin_bit_cast(uint32_t, __builtin_amdgcn_cvt_pkrtz(a, b));
}

#define HP 136  // hT row: 128 ch + 8 pad (272B stride: 16B-aligned, 2-way banks)

__global__ __launch_bounds__(512, 4) void cin_main(
    const float* __restrict__ x, const uint16_t* __restrict__ wp,
    const float* __restrict__ bias0, const float* __restrict__ bias1,
    const float* __restrict__ bias2, float* __restrict__ out) {
  __shared__ __align__(16) uint16_t hT[2][64][HP];  // [batch][d][chan] fp16

  const int tid = threadIdx.x;
  const int w = tid >> 6, lane = tid & 63;
  const int p = w >> 2;      // batch within block
  const int wg = w & 3;      // wave owns o-tiles {2wg, 2wg+1}
  const int q = lane >> 4;   // k-quad: B row k = q*8+j; C row o = q*4+r
  const int i = lane & 15;   // d within tile (B/C col); A row o (mod 16)
  const int bb = blockIdx.x * 2;

  // ---- stage x -> hT[p][d][m] fp16 (layer-0 h == x; 32 channels)
  for (int e = tid; e < 4096; e += 512) {
    int p2 = e >> 11, m = (e >> 6) & 31, d = e & 63;
    hT[p2][d][m] =
        __builtin_bit_cast(uint16_t, (_Float16)x[(size_t)(bb + p2) * 2048 + m * 64 + d]);
  }
  __syncthreads();

  // ---- x B-frags (loop-invariant): xf[t].j = x[m=q*8+j][d=t*16+i]
  AB xf[4];
#pragma unroll
  for (int t = 0; t < 4; ++t)
    xf[t].i = *(const i32x4*)&hT[p][t * 16 + i][q * 8];  // ds_read_b128

  f32x4 acc[4][2];  // [t][g] : 8 independent chains

#pragma unroll
  for (int L = 0; L < 3; ++L) {
    const int Kch = (L == 0) ? 32 : 128;
    const uint16_t* wl = (L == 0) ? wp : (L == 1) ? wp + 131072 : wp + 655360;
    const float* bias = (L == 0) ? bias0 : (L == 1) ? bias1 : bias2;

    // packed W frag elems: (ot*Kch + c)*512 + lane*8
    const uint16_t* wptr0 = wl + (size_t)(2 * wg + 0) * Kch * 512 + lane * 8;
    const uint16_t* wptr1 = wl + (size_t)(2 * wg + 1) * Kch * 512 + lane * 8;

#pragma unroll
    for (int t = 0; t < 4; ++t)
#pragma unroll
      for (int g = 0; g < 2; ++g) acc[t][g] = (f32x4){0.f, 0.f, 0.f, 0.f};

    AB wbuf[2][2][2];  // [slot][cc][g] : 32 VGPRs, depth-2 rotation
    uint32_t hvA[4], hvB[4];

    auto loadSlot = [&](int s, int c) {
      int cw = (c < Kch) ? c : 0;  // wrap: harmless dummy reload
#pragma unroll
      for (int cc = 0; cc < 2; ++cc) {
        wbuf[s][cc][0].i = *(const i32x4*)(wptr0 + (size_t)(cw + cc) * 512);
        wbuf[s][cc][1].i = *(const i32x4*)(wptr1 + (size_t)(cw + cc) * 512);
      }
    };
    auto loadHv = [&](uint32_t (&hv)[4], int c) {
      int cw = (c < Kch) ? c : 0;
#pragma unroll
      for (int t = 0; t < 4; ++t)
        hv[t] = *(const uint32_t*)&hT[p][t * 16 + i][cw];  // channels cw, cw+1
    };
    auto computePair = [&](const AB (&wb)[2][2], const uint32_t (&hv)[4]) {
#pragma unroll
      for (int cc = 0; cc < 2; ++cc)
#pragma unroll
        for (int t = 0; t < 4; ++t) {
          uint32_t hd = __builtin_amdgcn_perm(hv[t], hv[t],
                                              cc ? 0x03020302u : 0x01000100u);
          AB bf;  // B-frag: P[c*32 + q*8+j][d] = h[c,d] * x[q*8+j,d]
#pragma unroll
          for (int k = 0; k < 4; ++k) bf.u[k] = pkmul(hd, xf[t].u[k]);
          acc[t][0] = __builtin_amdgcn_mfma_f32_16x16x32_f16(wb[cc][0].h, bf.h, acc[t][0], 0, 0, 0);
          acc[t][1] = __builtin_amdgcn_mfma_f32_16x16x32_f16(wb[cc][1].h, bf.h, acc[t][1], 0, 0, 0);
        }
    };

    // prologue: slots hold pairs 0 and 2; hvA holds pair 0
    loadSlot(0, 0);
    loadSlot(1, 2);
    loadHv(hvA, 0);

#pragma unroll 1
    for (int c0 = 0; c0 < Kch; c0 += 4) {
      loadHv(hvB, c0 + 2);            // LDS prefetch for pair c0+2
      computePair(wbuf[0], hvA);      // consume pair c0 ...
      loadSlot(0, c0 + 4);            // ... THEN reload slot 0 (pair c0+4)
      __builtin_amdgcn_sched_barrier(0);  // pin load issue here
      loadHv(hvA, c0 + 4);
      computePair(wbuf[1], hvB);      // consume pair c0+2 ...
      loadSlot(1, c0 + 6);            // ... THEN reload slot 1 (pair c0+6)
      __builtin_amdgcn_sched_barrier(0);
    }

    // ---- bias + ReLU (C layout: o = ot*16 + q*4 + r, d = t*16 + i)
    f32x4 bv[2];
    bv[0] = *(const f32x4*)(bias + (2 * wg + 0) * 16 + q * 4);
    bv[1] = *(const f32x4*)(bias + (2 * wg + 1) * 16 + q * 4);
#pragma unroll
    for (int t = 0; t < 4; ++t)
#pragma unroll
      for (int g = 0; g < 2; ++g)
#pragma unroll
        for (int r = 0; r < 4; ++r)
          acc[t][g][r] = fmaxf(acc[t][g][r] + bv[g][r], 0.f);

    if (L < 2) {
      __syncthreads();  // all waves done READING hT before overwrite
#pragma unroll
      for (int t = 0; t < 4; ++t)
#pragma unroll
        for (int g = 0; g < 2; ++g) {
          uint2 pk;  // next-layer h channels o = (2wg+g)*16 + q*4 + r
          pk.x = pkcvt(acc[t][g][0], acc[t][g][1]);
          pk.y = pkcvt(acc[t][g][2], acc[t][g][3]);
          *(uint2*)&hT[p][t * 16 + i][(2 * wg + g) * 16 + q * 4] = pk;
        }
    }

    // d-sum: in-register over t, then xor-shuffle the 16 i-lanes
#pragma unroll
    for (int g = 0; g < 2; ++g)
#pragma unroll
      for (int r = 0; r < 4; ++r) {
        float s = acc[0][g][r] + acc[1][g][r] + acc[2][g][r] + acc[3][g][r];
        s += __shfl_xor(s, 1);
        s += __shfl_xor(s, 2);
        s += __shfl_xor(s, 4);
        s += __shfl_xor(s, 8);
        if (i == 0)
          out[(size_t)(bb + p) * 384 + L * 128 + (2 * wg + g) * 16 + q * 4 + r] = s;
      }

    if (L < 2) __syncthreads();  // hT writes visible before next K-loop
  }
}

// One pack kernel for all 3 layers. Reads coalesced along k (thread = (o,kq),
// 8 consecutive floats); writes fp16 frags: dst elem (ot*Kch+c)*512 + q*128 + i*8
// == (ot*Kch+c)*512 + lane*8 with lane = q*16+i (verified identical to R3's
// pack layout, which passed correctness).
__global__ void pack_w_all(const float* __restrict__ W0, const float* __restrict__ W1,
                           const float* __restrict__ W2, uint16_t* __restrict__ Wp) {
  int blk = blockIdx.x;
  const float* W;
  uint16_t* dst;
  int kshift;
  if (blk < 64)       { W = W0; dst = Wp;          kshift = 5; }
  else if (blk < 320) { W = W1; dst = Wp + 131072; kshift = 7; blk -= 64; }
  else                { W = W2; dst = Wp + 655360; kshift = 7; blk -= 320; }
  int idx = blk * 256 + threadIdx.x;
  int Kq = 1 << (kshift + 2);        // Kch*4 = K/8
  int o = idx >> (kshift + 2);
  int kq = idx & (Kq - 1);
  int c = kq >> 2, q = kq & 3;
  int ot = o >> 4, ii = o & 15;
  const float* src = W + ((size_t)o << (kshift + 5)) + kq * 8;
  uint4 val;
  val.x = pkcvt(src[0], src[1]);
  val.y = pkcvt(src[2], src[3]);
  val.z = pkcvt(src[4], src[5]);
  val.w = pkcvt(src[6], src[7]);
  *(uint4*)(dst + ((((size_t)ot << kshift) + c) << 9) + (q << 7) + (ii << 3)) = val;
}

extern "C" void kernel_launch(void* const* d_in, const int* in_sizes, int n_in,
                              void* d_out, int out_size, void* d_ws, size_t ws_size,
                              hipStream_t stream) {
  (void)in_sizes; (void)n_in; (void)out_size; (void)ws_size;
  const float* x  = (const float*)d_in[0];
  const float* W0 = (const float*)d_in[1];
  const float* b0 = (const float*)d_in[2];
  const float* W1 = (const float*)d_in[3];
  const float* b1 = (const float*)d_in[4];
  const float* W2 = (const float*)d_in[5];
  const float* b2 = (const float*)d_in[6];
  uint16_t* wpacked = (uint16_t*)d_ws;  // 2.25 MB of ws

  hipLaunchKernelGGL(pack_w_all, dim3(576), dim3(256), 0, stream, W0, W1, W2, wpacked);
  hipLaunchKernelGGL(cin_main, dim3(512), dim3(512), 0, stream,
                     x, wpacked, b0, b1, b2, (float*)d_out);
}